// Round 3
// baseline (937.231 us; speedup 1.0000x reference)
//
#include <hip/hip_runtime.h>
#include <hip/hip_bf16.h>
#include <math.h>

// ---------------------------------------------------------------------------
// 2-layer GCN (PyG GCNConv), fp32, CSR-gather aggregation.
//   deg[i]  = 1 + sum_{e: dst==i} w[e]; dinv = rsqrt(deg)
//   CSR: for each dst node, list of (src, norm=dinv[s]*w*dinv[d])
//   h1      = x @ W1
//   agg1[i] = dinv[i]^2*h1[i] + sum_{e in CSR[i]} norm*h1[src]
//   h2      = relu(agg1+b1) @ W2
//   out[i]  = dinv[i]^2*h2[i] + sum norm*h2[src];  out = log_softmax(out+b2)
// edge_index arrives as int32 (harness converts integer inputs to int32).
// ---------------------------------------------------------------------------

__global__ void k_zero2(float* __restrict__ a, int* __restrict__ b, int n) {
    int i = blockIdx.x * blockDim.x + threadIdx.x;
    if (i < n) { a[i] = 0.0f; b[i] = 0; }
}

__global__ void k_count_deg(const int* __restrict__ dst, const float* __restrict__ w,
                            float* __restrict__ degw, int* __restrict__ cnt, int E) {
    int e = blockIdx.x * blockDim.x + threadIdx.x;
    if (e < E) {
        int d = dst[e];
        atomicAdd(&degw[d], w[e]);
        atomicAdd(&cnt[d], 1);
    }
}

// dinv = rsqrt(1 + degw)  (self-loop weight 1; always > 0)
__global__ void k_dinv(float* __restrict__ degw, int n) {
    int i = blockIdx.x * blockDim.x + threadIdx.x;
    if (i < n) degw[i] = rsqrtf(1.0f + degw[i]);
}

// Exclusive scan of cnt[n] -> rowptr[n+1], cursor[n]. Single block, 1024 thr.
__global__ __launch_bounds__(1024) void k_scan(const int* __restrict__ cnt,
                                               int* __restrict__ rowptr,
                                               int* __restrict__ cursor, int n, int E) {
    __shared__ int sums[1024];
    int t = threadIdx.x;
    int chunk = (n + 1023) >> 10;
    int lo = t * chunk, hi = min(lo + chunk, n);
    int s = 0;
    for (int i = lo; i < hi; ++i) s += cnt[i];
    sums[t] = s;
    __syncthreads();
    for (int off = 1; off < 1024; off <<= 1) {
        int v = (t >= off) ? sums[t - off] : 0;
        __syncthreads();
        sums[t] += v;
        __syncthreads();
    }
    int pre = (t == 0) ? 0 : sums[t - 1];
    for (int i = lo; i < hi; ++i) {
        rowptr[i] = pre;
        cursor[i] = pre;
        pre += cnt[i];
    }
    if (t == 0) rowptr[n] = E;
}

// Scatter edges into CSR slots: csr[pos] = (src, norm) packed in 8B.
__global__ void k_reorder(const int* __restrict__ src, const int* __restrict__ dst,
                          const float* __restrict__ w, const float* __restrict__ dinv,
                          int* __restrict__ cursor, uint2* __restrict__ csr, int E) {
    int e = blockIdx.x * blockDim.x + threadIdx.x;
    if (e >= E) return;
    int d = dst[e], s = src[e];
    float nrm = dinv[s] * w[e] * dinv[d];
    int pos = atomicAdd(&cursor[d], 1);
    csr[pos] = make_uint2((unsigned)s, __float_as_uint(nrm));
}

// Gather aggregation: CH lanes own node i (lane c = channel). Self-loop folded
// into init. csr pair load is broadcast across the CH lanes (1 transaction);
// h gather is CH consecutive floats (one 4*CH-byte line from L2/L3).
template <int CH>
__global__ __launch_bounds__(256) void k_agg(const int* __restrict__ rowptr,
                                             const uint2* __restrict__ csr,
                                             const float* __restrict__ dinv,
                                             const float* __restrict__ h,
                                             float* __restrict__ outp, int n) {
    int t = blockIdx.x * 256 + threadIdx.x;
    int i = t / CH, c = t % CH;
    if (i >= n) return;
    float dv = dinv[i];
    float acc = dv * dv * h[(size_t)i * CH + c];
    int e1 = rowptr[i + 1];
    for (int e = rowptr[i]; e < e1; ++e) {
        uint2 p = csr[e];
        acc = fmaf(__uint_as_float(p.y), h[(size_t)p.x * CH + c], acc);
    }
    outp[(size_t)i * CH + c] = acc;
}

// h1 = x @ W1. 4 waves/block, wave = 4 rows x 16 cols; x read via float4
// broadcast (each element once from HBM); W1^T in LDS, stride 516.
__global__ __launch_bounds__(256) void k_gemm1(const float* __restrict__ x,
                                               const float* __restrict__ W1,
                                               float* __restrict__ h1, int n) {
    __shared__ float Wt[16 * 516];
    int tid = threadIdx.x;
    for (int idx = tid; idx < 512 * 16; idx += 256) {
        int k = idx >> 4, c = idx & 15;
        Wt[c * 516 + k] = W1[idx];
    }
    __syncthreads();
    int wave = tid >> 6, lane = tid & 63;
    int c = lane & 15, r = lane >> 4;
    int row = blockIdx.x * 16 + wave * 4 + r;
    if (row >= n) return;
    const float4* xr = (const float4*)(x + (size_t)row * 512);
    const float4* wr = (const float4*)(Wt + c * 516);
    float4 acc = make_float4(0.f, 0.f, 0.f, 0.f);
#pragma unroll 8
    for (int k4 = 0; k4 < 128; ++k4) {
        float4 xv = xr[k4];
        float4 wv = wr[k4];
        acc.x = fmaf(xv.x, wv.x, acc.x);
        acc.y = fmaf(xv.y, wv.y, acc.y);
        acc.z = fmaf(xv.z, wv.z, acc.z);
        acc.w = fmaf(xv.w, wv.w, acc.w);
    }
    h1[(size_t)row * 16 + c] = (acc.x + acc.y) + (acc.z + acc.w);
}

// h2 = relu(agg1 + b1) @ W2   [n,16]x[16,8]; 8 lanes per row.
__global__ __launch_bounds__(256) void k_gemm2(const float* __restrict__ agg1,
                                               const float* __restrict__ b1,
                                               const float* __restrict__ W2,
                                               float* __restrict__ h2, int n) {
    __shared__ float w2s[16 * 8];
    __shared__ float b1s[16];
    int tid = threadIdx.x;
    if (tid < 128) w2s[tid] = W2[tid];
    if (tid < 16) b1s[tid] = b1[tid];
    __syncthreads();
    int t = blockIdx.x * 256 + tid;
    int i = t >> 3, cc = t & 7;
    if (i >= n) return;
    const float* a = agg1 + (size_t)i * 16;
    float acc = 0.f;
#pragma unroll
    for (int k = 0; k < 16; ++k) {
        float v = fmaxf(a[k] + b1s[k], 0.f);
        acc = fmaf(v, w2s[k * 8 + cc], acc);
    }
    h2[(size_t)i * 8 + cc] = acc;
}

__global__ void k_logsoftmax(float* __restrict__ out, const float* __restrict__ b2, int n) {
    int i = blockIdx.x * blockDim.x + threadIdx.x;
    if (i >= n) return;
    float v[8];
#pragma unroll
    for (int c = 0; c < 8; ++c) v[c] = out[(size_t)i * 8 + c] + b2[c];
    float m = v[0];
#pragma unroll
    for (int c = 1; c < 8; ++c) m = fmaxf(m, v[c]);
    float s = 0.f;
#pragma unroll
    for (int c = 0; c < 8; ++c) s += expf(v[c] - m);
    float l = m + logf(s);
#pragma unroll
    for (int c = 0; c < 8; ++c) out[(size_t)i * 8 + c] = v[c] - l;
}

// -------------------- fallback (atomic scatter) kernels --------------------
__global__ void k_init_deg(float* __restrict__ deg, int n) {
    int i = blockIdx.x * blockDim.x + threadIdx.x;
    if (i < n) deg[i] = 1.0f;
}
__global__ void k_deg_scatter(const int* __restrict__ dst, const float* __restrict__ w,
                              float* __restrict__ deg, int E) {
    int e = blockIdx.x * blockDim.x + threadIdx.x;
    if (e < E) atomicAdd(&deg[dst[e]], w[e]);
}
__global__ void k_rsqrt_inplace(float* __restrict__ deg, int n) {
    int i = blockIdx.x * blockDim.x + threadIdx.x;
    if (i < n) { float d = deg[i]; deg[i] = d > 0.0f ? rsqrtf(d) : 0.0f; }
}
template <int CH>
__global__ void k_self_init(const float* __restrict__ dinv, const float* __restrict__ h,
                            float* __restrict__ agg, int n) {
    int t = blockIdx.x * blockDim.x + threadIdx.x;
    int i = t / CH;
    if (i < n) { float dv = dinv[i]; agg[t] = dv * dv * h[t]; }
}
template <int CH>
__global__ void k_scatter(const int* __restrict__ src, const int* __restrict__ dst,
                          const float* __restrict__ w, const float* __restrict__ dinv,
                          const float* __restrict__ h, float* __restrict__ agg, int E) {
    int t = blockIdx.x * blockDim.x + threadIdx.x;
    int e = t / CH, c = t % CH;
    if (e >= E) return;
    int s = src[e], d = dst[e];
    float nrm = dinv[s] * w[e] * dinv[d];
    atomicAdd(&agg[(size_t)d * CH + c], nrm * h[(size_t)s * CH + c]);
}
// ---------------------------------------------------------------------------

extern "C" void kernel_launch(void* const* d_in, const int* in_sizes, int n_in,
                              void* d_out, int out_size, void* d_ws, size_t ws_size,
                              hipStream_t stream) {
    const float* x  = (const float*)d_in[0];
    const int*   ei = (const int*)d_in[1];   // int32 per harness convention
    const float* ew = (const float*)d_in[2];
    const float* W1 = (const float*)d_in[3];
    const float* b1 = (const float*)d_in[4];
    const float* W2 = (const float*)d_in[5];
    const float* b2 = (const float*)d_in[6];
    float* out      = (float*)d_out;

    const int n = in_sizes[0] / 512;
    const int E = in_sizes[2];
    const int* src = ei;
    const int* dst = ei + E;

    const int B = 256;
    const int gn  = (n + B - 1) / B;
    const int gE  = (E + B - 1) / B;

    // CSR-path workspace layout (16B-aligned chunks):
    // h1[16n] | agg1[16n] | csr[E uint2] | deg[n] | rowptr[n+4] | cursor[n]
    size_t off_h1   = 0;
    size_t off_agg1 = off_h1 + (size_t)16 * n * 4;
    size_t off_csr  = off_agg1 + (size_t)16 * n * 4;
    size_t off_deg  = off_csr + (size_t)E * 8;
    size_t off_rp   = off_deg + (size_t)n * 4;
    size_t off_cur  = off_rp + (size_t)(n + 4) * 4;
    size_t need     = off_cur + (size_t)n * 4;

    if (ws_size >= need) {
        char* ws = (char*)d_ws;
        float* h1     = (float*)(ws + off_h1);
        float* h2     = h1;  // h1 dead once agg1 built
        float* agg1   = (float*)(ws + off_agg1);
        uint2* csr    = (uint2*)(ws + off_csr);
        float* deg    = (float*)(ws + off_deg);
        int*   rowptr = (int*)(ws + off_rp);
        int*   cursor = (int*)(ws + off_cur);
        int*   cnt    = cursor;  // cnt lives in cursor until scan copies it

        // cnt must be a distinct buffer from cursor during scan; reuse rowptr
        // region is unsafe. Use: cnt = cursor (counted first), scan reads cnt
        // and writes rowptr + re-derives cursor... but scan writes cursor while
        // reading cnt at the same index AFTER reading -> do it carefully:
        // k_scan reads cnt[i] then overwrites cursor[i]=rowptr-value. Since
        // cnt aliases cursor and each i is read before written in the same
        // thread's sequential loop, this is safe.

        k_zero2<<<gn, B, 0, stream>>>(deg, cnt, n);
        k_count_deg<<<gE, B, 0, stream>>>(dst, ew, deg, cnt, E);
        k_dinv<<<gn, B, 0, stream>>>(deg, n);
        k_scan<<<1, 1024, 0, stream>>>(cnt, rowptr, cursor, n, E);
        k_reorder<<<gE, B, 0, stream>>>(src, dst, ew, deg, cursor, csr, E);

        k_gemm1<<<(n + 15) / 16, B, 0, stream>>>(x, W1, h1, n);
        k_agg<16><<<((size_t)16 * n + B - 1) / B, B, 0, stream>>>(rowptr, csr, deg, h1, agg1, n);
        k_gemm2<<<((size_t)8 * n + B - 1) / B, B, 0, stream>>>(agg1, b1, W2, h2, n);
        k_agg<8><<<((size_t)8 * n + B - 1) / B, B, 0, stream>>>(rowptr, csr, deg, h2, out, n);
        k_logsoftmax<<<gn, B, 0, stream>>>(out, b2, n);
    } else {
        // fallback: atomic-scatter path (33n floats)
        float* deg  = (float*)d_ws;
        float* h1   = deg + n;
        float* h2   = h1;
        float* agg1 = h1 + (size_t)16 * n;

        k_init_deg<<<gn, B, 0, stream>>>(deg, n);
        k_deg_scatter<<<gE, B, 0, stream>>>(dst, ew, deg, E);
        k_rsqrt_inplace<<<gn, B, 0, stream>>>(deg, n);
        k_gemm1<<<(n + 15) / 16, B, 0, stream>>>(x, W1, h1, n);
        k_self_init<16><<<((size_t)16 * n + B - 1) / B, B, 0, stream>>>(deg, h1, agg1, n);
        k_scatter<16><<<((size_t)16 * E + B - 1) / B, B, 0, stream>>>(src, dst, ew, deg, h1, agg1, E);
        k_gemm2<<<((size_t)8 * n + B - 1) / B, B, 0, stream>>>(agg1, b1, W2, h2, n);
        k_self_init<8><<<((size_t)8 * n + B - 1) / B, B, 0, stream>>>(deg, h2, out, n);
        k_scatter<8><<<((size_t)8 * E + B - 1) / B, B, 0, stream>>>(src, dst, ew, deg, h2, out, E);
        k_logsoftmax<<<gn, B, 0, stream>>>(out, b2, n);
    }
}

// Round 4
// 711.872 us; speedup vs baseline: 1.3166x; 1.3166x over previous
//
#include <hip/hip_runtime.h>
#include <hip/hip_bf16.h>
#include <math.h>

// ---------------------------------------------------------------------------
// 2-layer GCN (PyG GCNConv), fp32. Atomic-free bucket-sorted aggregation.
//   Buckets of 64 dst-nodes; edges bucket-sorted via histogram+scan (exact,
//   no slack, no global atomics). Per-bucket LDS accumulation for deg and
//   both aggregations. gemm2 fused into agg16 epilogue; log_softmax fused
//   into agg8 epilogue.
// edge_index arrives as int32 (harness converts integer inputs to int32).
// ---------------------------------------------------------------------------

#define NBLK 256        // blocks in hist/bin passes (also threads in colscan)
#define MAX_NBK 2048    // max buckets supported by LDS arrays (n <= 131072)

// Pass A: per-block histogram of dst>>6 over this block's edge chunk.
__global__ __launch_bounds__(256) void k_hist(const int* __restrict__ dst,
                                              int* __restrict__ bh,
                                              int NBK, int E, int chunk) {
    __shared__ int hist[MAX_NBK];
    int blk = blockIdx.x, tid = threadIdx.x;
    for (int b = tid; b < NBK; b += 256) hist[b] = 0;
    __syncthreads();
    int lo = blk * chunk, hi = min(lo + chunk, E);
    for (int e = lo + tid; e < hi; e += 256) atomicAdd(&hist[dst[e] >> 6], 1);
    __syncthreads();
    for (int b = tid; b < NBK; b += 256) bh[(size_t)blk * NBK + b] = hist[b];
}

// Pass B1: per-bucket exclusive scan over the 256 block counts (in place);
// totals[b] = bucket total.
__global__ __launch_bounds__(256) void k_colscan(int* __restrict__ bh,
                                                 int* __restrict__ totals, int NBK) {
    __shared__ int s[256];
    int b = blockIdx.x, t = threadIdx.x;
    int v = bh[(size_t)t * NBK + b];
    s[t] = v;
    __syncthreads();
    for (int off = 1; off < 256; off <<= 1) {
        int u = (t >= off) ? s[t - off] : 0;
        __syncthreads();
        s[t] += u;
        __syncthreads();
    }
    bh[(size_t)t * NBK + b] = s[t] - v;  // exclusive prefix within bucket
    if (t == 255) totals[b] = s[255];
}

// Pass B2: exclusive scan of bucket totals -> bucketStart[NBK+1].
__global__ __launch_bounds__(256) void k_scan_totals(const int* __restrict__ totals,
                                                     int* __restrict__ bs,
                                                     int NBK, int E) {
    __shared__ int s[256];
    int t = threadIdx.x;
    int chunk = (NBK + 255) >> 8;
    int lo = t * chunk, hi = min(lo + chunk, NBK);
    int acc = 0;
    for (int i = lo; i < hi; ++i) acc += totals[i];
    s[t] = acc;
    __syncthreads();
    for (int off = 1; off < 256; off <<= 1) {
        int u = (t >= off) ? s[t - off] : 0;
        __syncthreads();
        s[t] += u;
        __syncthreads();
    }
    int pre = (t == 0) ? 0 : s[t - 1];
    for (int i = lo; i < hi; ++i) { bs[i] = pre; pre += totals[i]; }
    if (t == 0) bs[NBK] = E;
}

// Pass C: scatter edges into bucket regions. Each (block,bucket) slice is
// exclusively owned (offset = bucketStart + this block's scanned prefix), so
// LDS cursors suffice — zero global atomics. Edge packed: src | dstlow<<20.
__global__ __launch_bounds__(256) void k_bin(const int* __restrict__ src,
                                             const int* __restrict__ dst,
                                             const float* __restrict__ w,
                                             const int* __restrict__ bh,
                                             const int* __restrict__ bs,
                                             uint2* __restrict__ ebuf,
                                             int NBK, int E, int chunk) {
    __shared__ int cur[MAX_NBK];
    int blk = blockIdx.x, tid = threadIdx.x;
    for (int b = tid; b < NBK; b += 256)
        cur[b] = bs[b] + bh[(size_t)blk * NBK + b];
    __syncthreads();
    int lo = blk * chunk, hi = min(lo + chunk, E);
    for (int e = lo + tid; e < hi; e += 256) {
        int d = dst[e];
        int b = d >> 6;
        int pos = atomicAdd(&cur[b], 1);  // LDS atomic
        ebuf[pos] = make_uint2((unsigned)src[e] | ((unsigned)(d & 63) << 20),
                               __float_as_uint(w[e]));
    }
}

// Per-bucket degree -> dinv = rsqrt(1 + sum w). LDS accumulation only.
__global__ __launch_bounds__(256) void k_deg_dinv(const uint2* __restrict__ ebuf,
                                                  const int* __restrict__ bs,
                                                  float* __restrict__ dinv, int n) {
    __shared__ float dw[64];
    int b = blockIdx.x, tid = threadIdx.x;
    if (tid < 64) dw[tid] = 1.0f;  // self-loop weight
    __syncthreads();
    int e0 = bs[b], e1 = bs[b + 1];
    for (int e = e0 + tid; e < e1; e += 256) {
        uint2 p = ebuf[e];
        atomicAdd(&dw[p.x >> 20], __uint_as_float(p.y));
    }
    __syncthreads();
    int node = b * 64 + tid;
    if (tid < 64 && node < n) dinv[node] = rsqrtf(dw[tid]);
}

// h1 = x @ W1. 4 waves/block, wave = 4 rows x 16 cols; x via float4 broadcast
// (each element read once from HBM); W1^T in LDS, stride 516.
__global__ __launch_bounds__(256) void k_gemm1(const float* __restrict__ x,
                                               const float* __restrict__ W1,
                                               float* __restrict__ h1, int n) {
    __shared__ float Wt[16 * 516];
    int tid = threadIdx.x;
    for (int idx = tid; idx < 512 * 16; idx += 256) {
        int k = idx >> 4, c = idx & 15;
        Wt[c * 516 + k] = W1[idx];
    }
    __syncthreads();
    int wave = tid >> 6, lane = tid & 63;
    int c = lane & 15, r = lane >> 4;
    int row = blockIdx.x * 16 + wave * 4 + r;
    if (row >= n) return;
    const float4* xr = (const float4*)(x + (size_t)row * 512);
    const float4* wr = (const float4*)(Wt + c * 516);
    float4 acc = make_float4(0.f, 0.f, 0.f, 0.f);
#pragma unroll 8
    for (int k4 = 0; k4 < 128; ++k4) {
        float4 xv = xr[k4];
        float4 wv = wr[k4];
        acc.x = fmaf(xv.x, wv.x, acc.x);
        acc.y = fmaf(xv.y, wv.y, acc.y);
        acc.z = fmaf(xv.z, wv.z, acc.z);
        acc.w = fmaf(xv.w, wv.w, acc.w);
    }
    h1[(size_t)row * 16 + c] = (acc.x + acc.y) + (acc.z + acc.w);
}

// Layer-1 aggregation (LDS accumulate) fused with gemm2 epilogue:
//   acc[64x16] = dinv^2*h1 + sum nrm*h1[src];  h2 = relu(acc+b1) @ W2.
__global__ __launch_bounds__(256) void k_agg16g2(const uint2* __restrict__ ebuf,
                                                 const int* __restrict__ bs,
                                                 const float* __restrict__ dinv,
                                                 const float* __restrict__ h1,
                                                 const float* __restrict__ W2,
                                                 const float* __restrict__ b1,
                                                 float* __restrict__ h2, int n) {
    __shared__ float acc[64 * 17];  // stride 17: spreads LDS banks
    __shared__ float dloc[64];
    __shared__ float w2s[16 * 8];
    __shared__ float b1s[16];
    int b = blockIdx.x, tid = threadIdx.x;
    int nodeBase = b * 64;
    if (tid < 128) w2s[tid] = W2[tid];
    if (tid < 16) b1s[tid] = b1[tid];
    if (tid < 64) {
        int node = nodeBase + tid;
        dloc[tid] = (node < n) ? dinv[node] : 0.f;
    }
    __syncthreads();
    for (int o = tid; o < 64 * 16; o += 256) {
        int l = o >> 4, c = o & 15;
        int node = nodeBase + l;
        float v = 0.f;
        if (node < n) {
            float dv = dloc[l];
            v = dv * dv * h1[(size_t)node * 16 + c];
        }
        acc[l * 17 + c] = v;
    }
    __syncthreads();
    int e0 = bs[b], e1 = bs[b + 1];
    int g = tid >> 4, c = tid & 15;  // 16 groups x 16 channel-lanes
    for (int e = e0 + g; e < e1; e += 16) {
        uint2 p = ebuf[e];
        int s = p.x & 0xFFFFF;
        int dl = p.x >> 20;
        float nrm = dinv[s] * __uint_as_float(p.y) * dloc[dl];
        atomicAdd(&acc[dl * 17 + c], nrm * h1[(size_t)s * 16 + c]);
    }
    __syncthreads();
    // fused gemm2: h2[64x8] = relu(acc + b1) @ W2
    for (int o = tid; o < 64 * 8; o += 256) {
        int l = o >> 3, cc = o & 7;
        int node = nodeBase + l;
        if (node >= n) continue;
        float s = 0.f;
#pragma unroll
        for (int k = 0; k < 16; ++k) {
            float v = fmaxf(acc[l * 17 + k] + b1s[k], 0.f);
            s = fmaf(v, w2s[k * 8 + cc], s);
        }
        h2[(size_t)node * 8 + cc] = s;
    }
}

// Layer-2 aggregation fused with +b2 and log_softmax epilogue.
__global__ __launch_bounds__(256) void k_agg8lsm(const uint2* __restrict__ ebuf,
                                                 const int* __restrict__ bs,
                                                 const float* __restrict__ dinv,
                                                 const float* __restrict__ h2,
                                                 const float* __restrict__ b2,
                                                 float* __restrict__ out, int n) {
    __shared__ float acc[64 * 9];  // stride 9
    __shared__ float dloc[64];
    __shared__ float b2s[8];
    int b = blockIdx.x, tid = threadIdx.x;
    int nodeBase = b * 64;
    if (tid < 8) b2s[tid] = b2[tid];
    if (tid < 64) {
        int node = nodeBase + tid;
        dloc[tid] = (node < n) ? dinv[node] : 0.f;
    }
    __syncthreads();
    for (int o = tid; o < 64 * 8; o += 256) {
        int l = o >> 3, c = o & 7;
        int node = nodeBase + l;
        float v = 0.f;
        if (node < n) {
            float dv = dloc[l];
            v = dv * dv * h2[(size_t)node * 8 + c];
        }
        acc[l * 9 + c] = v;
    }
    __syncthreads();
    int e0 = bs[b], e1 = bs[b + 1];
    int g = tid >> 3, c = tid & 7;  // 32 groups x 8 channel-lanes
    for (int e = e0 + g; e < e1; e += 32) {
        uint2 p = ebuf[e];
        int s = p.x & 0xFFFFF;
        int dl = p.x >> 20;
        float nrm = dinv[s] * __uint_as_float(p.y) * dloc[dl];
        atomicAdd(&acc[dl * 9 + c], nrm * h2[(size_t)s * 8 + c]);
    }
    __syncthreads();
    // fused log_softmax: thread t (<64) owns one node's 8-channel row.
    if (tid < 64) {
        int node = nodeBase + tid;
        if (node < n) {
            float v[8];
#pragma unroll
            for (int cc = 0; cc < 8; ++cc) v[cc] = acc[tid * 9 + cc] + b2s[cc];
            float m = v[0];
#pragma unroll
            for (int cc = 1; cc < 8; ++cc) m = fmaxf(m, v[cc]);
            float sum = 0.f;
#pragma unroll
            for (int cc = 0; cc < 8; ++cc) sum += expf(v[cc] - m);
            float l = m + logf(sum);
#pragma unroll
            for (int cc = 0; cc < 8; ++cc) out[(size_t)node * 8 + cc] = v[cc] - l;
        }
    }
}

// -------------------- fallback (atomic scatter, proven correct) ------------
__global__ void k_init_deg(float* __restrict__ deg, int n) {
    int i = blockIdx.x * blockDim.x + threadIdx.x;
    if (i < n) deg[i] = 1.0f;
}
__global__ void k_deg_scatter(const int* __restrict__ dst, const float* __restrict__ w,
                              float* __restrict__ deg, int E) {
    int e = blockIdx.x * blockDim.x + threadIdx.x;
    if (e < E) atomicAdd(&deg[dst[e]], w[e]);
}
__global__ void k_rsqrt_inplace(float* __restrict__ deg, int n) {
    int i = blockIdx.x * blockDim.x + threadIdx.x;
    if (i < n) { float d = deg[i]; deg[i] = d > 0.0f ? rsqrtf(d) : 0.0f; }
}
template <int CH>
__global__ void k_self_init(const float* __restrict__ dinv, const float* __restrict__ h,
                            float* __restrict__ agg, int n) {
    int t = blockIdx.x * blockDim.x + threadIdx.x;
    int i = t / CH;
    if (i < n) { float dv = dinv[i]; agg[t] = dv * dv * h[t]; }
}
template <int CH>
__global__ void k_scatter(const int* __restrict__ src, const int* __restrict__ dst,
                          const float* __restrict__ w, const float* __restrict__ dinv,
                          const float* __restrict__ h, float* __restrict__ agg, int E) {
    int t = blockIdx.x * blockDim.x + threadIdx.x;
    int e = t / CH, c = t % CH;
    if (e >= E) return;
    int s = src[e], d = dst[e];
    float nrm = dinv[s] * w[e] * dinv[d];
    atomicAdd(&agg[(size_t)d * CH + c], nrm * h[(size_t)s * CH + c]);
}
__global__ __launch_bounds__(256) void k_gemm2(const float* __restrict__ agg1,
                                               const float* __restrict__ b1,
                                               const float* __restrict__ W2,
                                               float* __restrict__ h2, int n) {
    __shared__ float w2s[16 * 8];
    __shared__ float b1s[16];
    int tid = threadIdx.x;
    if (tid < 128) w2s[tid] = W2[tid];
    if (tid < 16) b1s[tid] = b1[tid];
    __syncthreads();
    int t = blockIdx.x * 256 + tid;
    int i = t >> 3, cc = t & 7;
    if (i >= n) return;
    const float* a = agg1 + (size_t)i * 16;
    float acc = 0.f;
#pragma unroll
    for (int k = 0; k < 16; ++k) {
        float v = fmaxf(a[k] + b1s[k], 0.f);
        acc = fmaf(v, w2s[k * 8 + cc], acc);
    }
    h2[(size_t)i * 8 + cc] = acc;
}
__global__ void k_logsoftmax(float* __restrict__ out, const float* __restrict__ b2, int n) {
    int i = blockIdx.x * blockDim.x + threadIdx.x;
    if (i >= n) return;
    float v[8];
#pragma unroll
    for (int c = 0; c < 8; ++c) v[c] = out[(size_t)i * 8 + c] + b2[c];
    float m = v[0];
#pragma unroll
    for (int c = 1; c < 8; ++c) m = fmaxf(m, v[c]);
    float s = 0.f;
#pragma unroll
    for (int c = 0; c < 8; ++c) s += expf(v[c] - m);
    float l = m + logf(s);
#pragma unroll
    for (int c = 0; c < 8; ++c) out[(size_t)i * 8 + c] = v[c] - l;
}
// ---------------------------------------------------------------------------

extern "C" void kernel_launch(void* const* d_in, const int* in_sizes, int n_in,
                              void* d_out, int out_size, void* d_ws, size_t ws_size,
                              hipStream_t stream) {
    const float* x  = (const float*)d_in[0];
    const int*   ei = (const int*)d_in[1];   // int32 per harness convention
    const float* ew = (const float*)d_in[2];
    const float* W1 = (const float*)d_in[3];
    const float* b1 = (const float*)d_in[4];
    const float* W2 = (const float*)d_in[5];
    const float* b2 = (const float*)d_in[6];
    float* out      = (float*)d_out;

    const int n = in_sizes[0] / 512;
    const int E = in_sizes[2];
    const int* src = ei;
    const int* dst = ei + E;

    const int B = 256;
    const int NBK = (n + 63) >> 6;
    const int chunk = (E + NBLK - 1) / NBLK;

    // ws: ebuf[E uint2] | h1[16n f32] | h2[8n] | blockHist[NBLK*NBK] |
    //     totals[NBK] | bs[NBK+1] | dinv[n]      (~37 MB)
    size_t off_ebuf = 0;
    size_t off_h1   = off_ebuf + (size_t)E * 8;
    size_t off_h2   = off_h1 + (size_t)16 * n * 4;
    size_t off_bh   = off_h2 + (size_t)8 * n * 4;
    size_t off_tot  = off_bh + (size_t)NBLK * NBK * 4;
    size_t off_bs   = off_tot + (size_t)NBK * 4;
    size_t off_dinv = off_bs + (size_t)(NBK + 1) * 4;
    size_t need     = off_dinv + (size_t)n * 4;

    if (ws_size >= need && NBK <= MAX_NBK && n <= (1 << 20)) {
        char* ws = (char*)d_ws;
        uint2* ebuf  = (uint2*)(ws + off_ebuf);
        float* h1    = (float*)(ws + off_h1);
        float* h2    = (float*)(ws + off_h2);
        int*   bh    = (int*)(ws + off_bh);
        int*   tot   = (int*)(ws + off_tot);
        int*   bs    = (int*)(ws + off_bs);
        float* dinv  = (float*)(ws + off_dinv);

        k_hist<<<NBLK, B, 0, stream>>>(dst, bh, NBK, E, chunk);
        k_colscan<<<NBK, B, 0, stream>>>(bh, tot, NBK);
        k_scan_totals<<<1, B, 0, stream>>>(tot, bs, NBK, E);
        k_bin<<<NBLK, B, 0, stream>>>(src, dst, ew, bh, bs, ebuf, NBK, E, chunk);
        k_deg_dinv<<<NBK, B, 0, stream>>>(ebuf, bs, dinv, n);

        k_gemm1<<<(n + 15) / 16, B, 0, stream>>>(x, W1, h1, n);
        k_agg16g2<<<NBK, B, 0, stream>>>(ebuf, bs, dinv, h1, W2, b1, h2, n);
        k_agg8lsm<<<NBK, B, 0, stream>>>(ebuf, bs, dinv, h2, b2, out, n);
    } else {
        // fallback: atomic-scatter path (33n floats)
        float* deg  = (float*)d_ws;
        float* h1   = deg + n;
        float* h2   = h1;
        float* agg1 = h1 + (size_t)16 * n;
        int gn = (n + B - 1) / B, gE = (E + B - 1) / B;

        k_init_deg<<<gn, B, 0, stream>>>(deg, n);
        k_deg_scatter<<<gE, B, 0, stream>>>(dst, ew, deg, E);
        k_rsqrt_inplace<<<gn, B, 0, stream>>>(deg, n);
        k_gemm1<<<(n + 15) / 16, B, 0, stream>>>(x, W1, h1, n);
        k_self_init<16><<<((size_t)16 * n + B - 1) / B, B, 0, stream>>>(deg, h1, agg1, n);
        k_scatter<16><<<((size_t)16 * E + B - 1) / B, B, 0, stream>>>(src, dst, ew, deg, h1, agg1, E);
        k_gemm2<<<((size_t)8 * n + B - 1) / B, B, 0, stream>>>(agg1, b1, W2, h2, n);
        k_self_init<8><<<((size_t)8 * n + B - 1) / B, B, 0, stream>>>(deg, h2, out, n);
        k_scatter<8><<<((size_t)8 * E + B - 1) / B, B, 0, stream>>>(src, dst, ew, deg, h2, out, E);
        k_logsoftmax<<<gn, B, 0, stream>>>(out, b2, n);
    }
}